// Round 1
// 167.398 us; speedup vs baseline: 1.0601x; 1.0601x over previous
//
#include <hip/hip_runtime.h>

#define B_   8
#define C_   256
#define W_   8192
#define F_   256
#define KK   3
#define KC   768            // KK * C_
#define WP   (W_ + 2)       // padded rows in featT (zero row at w=-1 and w=W)
#define COEF 0.03608439182435161f   // 1/sqrt(3*256)

// conv_mod geometry: BM=256 (all of F), BN=128 (w), BK=32, ring-3 LDS pipeline
#define BN_   128
#define BKc   32
#define NT    24            // 768 / 32 K-tiles
#define ASLOT 8192          // 256 rows * 32 k (ushort) = 16 KiB
#define BSLOT 4096          // 128 rows * 32 k (ushort) =  8 KiB
#define SLOT  12288         // ushorts per ring slot (24 KiB); ring = 3 slots = 72 KiB

using f32x16 = __attribute__((ext_vector_type(16))) float;
using bf16x8 = __attribute__((ext_vector_type(8))) __bf16;

#define AS1(p) ((const __attribute__((address_space(1))) void*)(p))
#define AS3(p) ((__attribute__((address_space(3))) void*)(p))

__device__ __forceinline__ unsigned short f2bf(float x) {
    union { float f; unsigned int u; } v; v.f = x;
    unsigned int u = v.u;
    u += 0x7FFFu + ((u >> 16) & 1u);   // RNE
    return (unsigned short)(u >> 16);
}

// Merged prep: blocks 0..7 compute denom (long pole, dispatched first);
// blocks 8..775 transpose kernel -> kT and zero featT's pad rows.
__global__ __launch_bounds__(256) void prep_w(const float* __restrict__ kern,
                                              const float* __restrict__ style,
                                              unsigned short* __restrict__ kT,
                                              float* __restrict__ denom,
                                              unsigned short* __restrict__ featT) {
    __shared__ float sst[C_];
    if (blockIdx.x < B_) {
        // denom[b][f] = rsqrt( sum_{k,c} (kern[k,c,f]*COEF*(style[b,c]+1))^2 )
        const int b = blockIdx.x, f = threadIdx.x;
        sst[f] = (style[b * C_ + f] + 1.0f) * COEF;
        __syncthreads();
        float sum = 0.f;
#pragma unroll 16
        for (int kc = 0; kc < KC; ++kc) {
            float w = kern[(size_t)kc * F_ + f] * sst[kc & 255];
            sum += w * w;
        }
        denom[b * F_ + f] = rsqrtf(sum);
    } else {
        const int idx = (blockIdx.x - B_) * 256 + threadIdx.x;   // ((k*256)+c)*256 + f
        const int f = idx & 255, kc = idx >> 8;
        kT[(size_t)f * KC + kc] = f2bf(kern[idx] * COEF);
        if (idx < 4096) {       // 8 b * 2 pad rows * 256 c
            const int b = idx >> 9, r = (idx >> 8) & 1, c = idx & 255;
            const size_t row = r ? (size_t)(WP - 1) : 0;
            featT[((size_t)b * WP + row) * C_ + c] = 0;
        }
    }
}

// featT[b][w+1][c] = bf16( feat[b][c][w] * (style[b][c]+1) )
// 64(c) x 64(w) tile: float4 loads, modulate, LDS transpose [w][c], uint4 stores
__global__ __launch_bounds__(256) void prep_featT(const float* __restrict__ feat,
                                                  const float* __restrict__ style,
                                                  unsigned short* __restrict__ featT) {
    __shared__ float tile[64][65];   // [w][c], 65 pad -> conflict-free both phases
    const int tid = threadIdx.x;
    const int b = blockIdx.z, c0 = blockIdx.y * 64, w0 = blockIdx.x * 64;

    const int x4 = tid & 15, cl4 = tid >> 4;
#pragma unroll
    for (int p = 0; p < 4; ++p) {
        const int cl = cl4 + p * 16;
        const float s = style[b * C_ + c0 + cl] + 1.0f;
        float4 v = *(const float4*)(feat + ((size_t)b * C_ + c0 + cl) * W_ + w0 + x4 * 4);
        tile[x4 * 4 + 0][cl] = v.x * s;
        tile[x4 * 4 + 1][cl] = v.y * s;
        tile[x4 * 4 + 2][cl] = v.z * s;
        tile[x4 * 4 + 3][cl] = v.w * s;
    }
    __syncthreads();

    const int ch = tid & 7, wr = tid >> 3;   // ch: 8-c chunk, wr: 0..31
#pragma unroll
    for (int p = 0; p < 2; ++p) {
        const int w = wr + p * 32;
        unsigned int pk[4];
#pragma unroll
        for (int j = 0; j < 4; ++j) {
            float v0 = tile[w][ch * 8 + 2 * j];
            float v1 = tile[w][ch * 8 + 2 * j + 1];
            pk[j] = (unsigned int)f2bf(v0) | ((unsigned int)f2bf(v1) << 16);
        }
        uint4 u; u.x = pk[0]; u.y = pk[1]; u.z = pk[2]; u.w = pk[3];
        *(uint4*)(featT + ((size_t)b * WP + (w0 + w + 1)) * C_ + c0 + ch * 8) = u;
    }
}

// One K-tile of MFMAs: 4 B-frags up front, then per-mi {2 A-frag reads, 4 MFMA}.
__device__ __forceinline__ void compute_tile(const unsigned short* __restrict__ sb,
                                             const int (&aoff)[4][2], const int (&boff)[2][2],
                                             f32x16 (&acc)[4][2]) {
    bf16x8 bf0 = *(const bf16x8*)&sb[boff[0][0]];
    bf16x8 bf1 = *(const bf16x8*)&sb[boff[1][0]];
    bf16x8 bg0 = *(const bf16x8*)&sb[boff[0][1]];
    bf16x8 bg1 = *(const bf16x8*)&sb[boff[1][1]];
#pragma unroll
    for (int mi = 0; mi < 4; ++mi) {
        bf16x8 a0 = *(const bf16x8*)&sb[aoff[mi][0]];
        bf16x8 a1 = *(const bf16x8*)&sb[aoff[mi][1]];
        acc[mi][0] = __builtin_amdgcn_mfma_f32_32x32x16_bf16(a0, bf0, acc[mi][0], 0, 0, 0);
        acc[mi][1] = __builtin_amdgcn_mfma_f32_32x32x16_bf16(a0, bf1, acc[mi][1], 0, 0, 0);
        acc[mi][0] = __builtin_amdgcn_mfma_f32_32x32x16_bf16(a1, bg0, acc[mi][0], 0, 0, 0);
        acc[mi][1] = __builtin_amdgcn_mfma_f32_32x32x16_bf16(a1, bg1, acc[mi][1], 0, 0, 0);
    }
}

// Main GEMM-conv: 256(f) x 128(w) block tile, 4 waves each 128x64 via 4x2 of
// 32x32x16 MFMA. Ring-3 LDS (24 KiB/slot), global_load_lds width=16 staging,
// chunk-XOR swizzle (pre-swizzled global source + matching read XOR).
// Pipeline: stage tile t+2 (-> slot (t-1)%3, freed one barrier ago), compute
// tile t, then sched_barrier(0); s_waitcnt vmcnt(6); s_barrier -- tile t+1's
// 6 loads retired, tile t+2's 6 stay in flight across the barrier (T3+T4).
__global__ __launch_bounds__(256, 2) void conv_mod(
        const unsigned short* __restrict__ featT,
        const unsigned short* __restrict__ kT,
        const float* __restrict__ denom,
        float* __restrict__ out) {
    __shared__ __align__(16) unsigned short ring[3 * SLOT];   // 72 KiB -> 2 blocks/CU

    const int tid  = threadIdx.x;
    const int b    = blockIdx.y;
    const int w0   = blockIdx.x * BN_;
    const int lane = tid & 63, wave = tid >> 6;
    const int wm   = (wave >> 1) * 128;   // wave f-offset
    const int wn   = (wave & 1) * 64;     // wave w-offset
    const int la   = lane & 31, kq = lane >> 5;

    // ---- staging: wave covers 16 rows/issue; lane l -> row +(l>>2), phys chunk
    //      l&3, global source logical chunk (l&3)^(row&3) (inverse swizzle) ----
    const int lrow = lane >> 2, lswz = (lane & 3) ^ (lrow & 3);
    const int r0 = wave * 16 + lrow;
    const unsigned short* asrc0 = kT + (size_t)(r0)       * KC + lswz * 8;
    const unsigned short* asrc1 = kT + (size_t)(r0 + 64)  * KC + lswz * 8;
    const unsigned short* asrc2 = kT + (size_t)(r0 + 128) * KC + lswz * 8;
    const unsigned short* asrc3 = kT + (size_t)(r0 + 192) * KC + lswz * 8;
    const unsigned short* bsrc0 = featT + ((size_t)b * WP + (w0 + r0))      * C_ + lswz * 8;
    const unsigned short* bsrc1 = featT + ((size_t)b * WP + (w0 + r0 + 64)) * C_ + lswz * 8;
    const int al0 = (wave * 16)       * BKc;
    const int al1 = (wave * 16 + 64)  * BKc;
    const int al2 = (wave * 16 + 128) * BKc;
    const int al3 = (wave * 16 + 192) * BKc;
    const int bl0 = ASLOT + (wave * 16)      * BKc;
    const int bl1 = ASLOT + (wave * 16 + 64) * BKc;

    // ---- fragment LDS offsets (ushort units, slot-relative) ----
    int aoff[4][2], boff[2][2];
#pragma unroll
    for (int mi = 0; mi < 4; ++mi) {
        const int row = wm + mi * 32 + la;
#pragma unroll
        for (int kh = 0; kh < 2; ++kh)
            aoff[mi][kh] = row * BKc + (((kh * 2 + kq) ^ (la & 3)) * 8);
    }
#pragma unroll
    for (int ni = 0; ni < 2; ++ni) {
        const int row = wn + ni * 32 + la;
#pragma unroll
        for (int kh = 0; kh < 2; ++kh)
            boff[ni][kh] = ASLOT + row * BKc + (((kh * 2 + kq) ^ (la & 3)) * 8);
    }

#define STAGE(t, s) do { \
        const int ko = (t) * BKc; \
        unsigned short* rs = &ring[(s) * SLOT]; \
        __builtin_amdgcn_global_load_lds(AS1(asrc0 + ko), AS3(rs + al0), 16, 0, 0); \
        __builtin_amdgcn_global_load_lds(AS1(asrc1 + ko), AS3(rs + al1), 16, 0, 0); \
        __builtin_amdgcn_global_load_lds(AS1(asrc2 + ko), AS3(rs + al2), 16, 0, 0); \
        __builtin_amdgcn_global_load_lds(AS1(asrc3 + ko), AS3(rs + al3), 16, 0, 0); \
        __builtin_amdgcn_global_load_lds(AS1(bsrc0 + ko), AS3(rs + bl0), 16, 0, 0); \
        __builtin_amdgcn_global_load_lds(AS1(bsrc1 + ko), AS3(rs + bl1), 16, 0, 0); \
    } while (0)

    // sched_barrier pins this iter's ds_reads/MFMAs above the wait (rule #18);
    // per-wave vmcnt BEFORE the barrier so all waves' tile t+1 loads are
    // retired when anyone proceeds; empty memory-clobber asm after the raw
    // barrier stops IR-level hoisting of next iter's LDS reads above it.
#define ITER_END(N) do { \
        __builtin_amdgcn_sched_barrier(0); \
        asm volatile("s_waitcnt vmcnt(" #N ")" ::: "memory"); \
        __builtin_amdgcn_s_barrier(); \
        asm volatile("" ::: "memory"); \
    } while (0)

    f32x16 acc[4][2] = {};

    // prologue: stage tiles 0,1; wait tile 0 (6 of 12 retired)
    STAGE(0, 0);
    STAGE(1, 1);
    asm volatile("s_waitcnt vmcnt(6)" ::: "memory");
    __builtin_amdgcn_s_barrier();
    asm volatile("" ::: "memory");

#pragma unroll 1
    for (int j = 0; j < 7; ++j) {        // tiles 0..20
        const int t = j * 3;
        STAGE(t + 2, 2);
        __builtin_amdgcn_s_setprio(1);
        compute_tile(&ring[0], aoff, boff, acc);
        __builtin_amdgcn_s_setprio(0);
        ITER_END(6);
        STAGE(t + 3, 0);
        __builtin_amdgcn_s_setprio(1);
        compute_tile(&ring[SLOT], aoff, boff, acc);
        __builtin_amdgcn_s_setprio(0);
        ITER_END(6);
        STAGE(t + 4, 1);
        __builtin_amdgcn_s_setprio(1);
        compute_tile(&ring[2 * SLOT], aoff, boff, acc);
        __builtin_amdgcn_s_setprio(0);
        ITER_END(6);
    }
    // t = 21: stage last tile (23 -> slot 2, freed after t=20)
    STAGE(23, 2);
    __builtin_amdgcn_s_setprio(1);
    compute_tile(&ring[0], aoff, boff, acc);
    __builtin_amdgcn_s_setprio(0);
    ITER_END(6);
    // t = 22
    __builtin_amdgcn_s_setprio(1);
    compute_tile(&ring[SLOT], aoff, boff, acc);
    __builtin_amdgcn_s_setprio(0);
    ITER_END(0);
    // t = 23
    __builtin_amdgcn_s_setprio(1);
    compute_tile(&ring[2 * SLOT], aoff, boff, acc);
    __builtin_amdgcn_s_setprio(0);

    // ---- epilogue: C/D layout for 32x32: col=lane&31, row=(reg&3)+8*(reg>>2)+4*(lane>>5)
    //      [measured m74/m101] ----
    const int bofs = b * F_;
    float* obase = out + (size_t)bofs * W_ + w0;
#pragma unroll
    for (int mi = 0; mi < 4; ++mi) {
#pragma unroll
        for (int r = 0; r < 16; ++r) {
            const int frow = (r & 3) + 8 * (r >> 2) + 4 * kq;
            const int f = wm + mi * 32 + frow;
            const float d = denom[bofs + f];
            float* orow = obase + (size_t)f * W_ + wn + la;
            orow[0]  = acc[mi][0][r] * d;
            orow[32] = acc[mi][1][r] * d;
        }
    }
#undef STAGE
#undef ITER_END
}

extern "C" void kernel_launch(void* const* d_in, const int* in_sizes, int n_in,
                              void* d_out, int out_size, void* d_ws, size_t ws_size,
                              hipStream_t stream) {
    const float* feature = (const float*)d_in[0];   // [8,256,8192]
    const float* style   = (const float*)d_in[1];   // [8,256]
    const float* kern    = (const float*)d_in[2];   // [3,256,256]
    float* out = (float*)d_out;                     // [8,256,8192]

    // ws layout: kT (384 KiB) | denom (8 KiB) | featT (8*8194*256 bf16 = 32.0 MiB)
    unsigned short* kT    = (unsigned short*)d_ws;
    float*          denom = (float*)((char*)d_ws + (size_t)F_ * KC * 2);
    unsigned short* featT = (unsigned short*)((char*)d_ws + (size_t)F_ * KC * 2 + 8192);

    hipLaunchKernelGGL(prep_w,     dim3(KC + B_), dim3(256), 0, stream,
                       kern, style, kT, denom, featT);
    hipLaunchKernelGGL(prep_featT, dim3(W_ / 64, C_ / 64, B_), dim3(256), 0, stream,
                       feature, style, featT);
    hipLaunchKernelGGL(conv_mod,   dim3(W_ / BN_, B_), dim3(256), 0, stream,
                       featT, kT, denom, out);
}